// Round 1
// baseline (988.761 us; speedup 1.0000x reference)
//
#include <hip/hip_runtime.h>
#include <hip/hip_bf16.h>
#include <stdint.h>

// BitSwarmLinear: out = x @ sign(population.sum(axis=2))^T
//   x:          (4, 4096, 2048) fp32  -> A, M=16384, K=2048
//   population: (2048, 2048, 32) fp32 -> reduced+signed -> W (N=2048, K=2048), values ±1
//   out:        (4, 4096, 2048) fp32  -> C, M x N

static constexpr int M_DIM = 16384;
static constexpr int N_DIM = 2048;
static constexpr int K_DIM = 2048;
static constexpr int SWARM = 32;

typedef __attribute__((ext_vector_type(8))) short short8;   // 8 x bf16 = 4 VGPRs
typedef __attribute__((ext_vector_type(4))) float f32x4;    // MFMA accumulator

// ---------------------------------------------------------------------------
// Kernel 1: swarm reduction + sign binarization.
// population is (N, K, 32) with swarm innermost: each output needs 32
// contiguous floats (128 B). 8 lanes cooperate per output (fully coalesced
// float4 loads), then 3 xor-shuffles reduce within the 8-lane group.
// sign(0) -> +1  ==>  (s >= 0) ? +1 : -1.
// ---------------------------------------------------------------------------
__global__ __launch_bounds__(256) void swarm_reduce(const float4* __restrict__ pop4,
                                                    ushort* __restrict__ W) {
    const int tid = blockIdx.x * 256 + threadIdx.x;   // one float4 per thread
    float4 v = pop4[tid];
    float s = v.x + v.y + v.z + v.w;
    s += __shfl_xor(s, 1);
    s += __shfl_xor(s, 2);
    s += __shfl_xor(s, 4);
    if ((threadIdx.x & 7) == 0) {
        // +1.0 bf16 = 0x3F80, -1.0 bf16 = 0xBF80 (exact)
        W[tid >> 3] = (s >= 0.0f) ? (ushort)0x3F80 : (ushort)0xBF80;
    }
}

// fp32 -> bf16 round-to-nearest-even (no NaN inputs here)
__device__ __forceinline__ ushort f2bf(float f) {
    uint32_t u = __float_as_uint(f);
    u += 0x7FFFu + ((u >> 16) & 1u);
    return (ushort)(u >> 16);
}

// ---------------------------------------------------------------------------
// Kernel 2: bf16 MFMA GEMM, C[m,n] = sum_k A[m,k] * W[n,k]  (B^T layout).
// 128x128 block tile, BK=32, 256 threads = 4 waves in 2x2, each wave owns a
// 64x64 sub-tile = 4x4 grid of 16x16x32 MFMAs.
//   - W tile (bf16) staged with global_load_lds width=16 (contiguous layout).
//   - A tile (fp32 source) staged via VGPRs with inline cvt to bf16.
// Fragment layouts (guide §3, HW-verified):
//   A[m = lane&15][k = 8*(lane>>4) + j]     (short8)
//   B[k = 8*(lane>>4) + j][n = lane&15]     (short8, == W[n][k] row-major read)
//   D[i = 4*(lane>>4) + r][j = lane&15]     (f32x4)
// ---------------------------------------------------------------------------
#define BM 128
#define BN 128
#define BK 32

__global__ __launch_bounds__(256) void gemm_bt(const float* __restrict__ A,
                                               const ushort* __restrict__ B,
                                               float* __restrict__ C) {
    __shared__ ushort la[BM * BK];   // 8 KiB, A tile as bf16, row-major [128][32]
    __shared__ ushort lb[BN * BK];   // 8 KiB, W tile,        row-major [128][32]

    const int t    = threadIdx.x;
    const int bm   = blockIdx.x;          // 0..127
    const int bn   = blockIdx.y;          // 0..15
    const int wave = t >> 6;
    const int lane = t & 63;
    const int wm   = (wave >> 1) * 64;    // wave sub-tile row offset
    const int wn   = (wave & 1) * 64;     // wave sub-tile col offset
    const int l16  = lane & 15;
    const int quad = lane >> 4;

    f32x4 acc[4][4];
    #pragma unroll
    for (int i = 0; i < 4; ++i)
        #pragma unroll
        for (int j = 0; j < 4; ++j)
            acc[i][j] = (f32x4){0.f, 0.f, 0.f, 0.f};

    const float*  Abase = A + (size_t)(bm * BM) * K_DIM;
    const ushort* Bbase = B + (size_t)(bn * BN) * K_DIM;

    for (int k0 = 0; k0 < K_DIM; k0 += BK) {
        // ---- stage W tile: async global->LDS, 16 B per lane, contiguous ----
        #pragma unroll
        for (int i = 0; i < 2; ++i) {
            const int c   = i * 256 + t;        // 16-byte chunk id, 512 total
            const int row = c >> 2;             // 4 chunks per 64 B row
            const int kc  = (c & 3) * 8;
            const ushort* g = Bbase + (size_t)row * K_DIM + k0 + kc;
            __builtin_amdgcn_global_load_lds(
                (const __attribute__((address_space(1))) void*)g,
                (__attribute__((address_space(3))) void*)(&lb[c * 8]),
                16, 0, 0);
        }
        // ---- stage A tile: fp32 load -> bf16 cvt -> LDS (8 B per store) ----
        #pragma unroll
        for (int i = 0; i < 4; ++i) {
            const int c   = i * 256 + t;        // float4 chunk id, 1024 total
            const int row = c >> 3;             // 8 float4 per 32-float row
            const int kc  = (c & 7) * 4;
            float4 v = *(const float4*)(Abase + (size_t)row * K_DIM + k0 + kc);
            union { uint2 u2; ushort s[4]; } pk;
            pk.s[0] = f2bf(v.x);
            pk.s[1] = f2bf(v.y);
            pk.s[2] = f2bf(v.z);
            pk.s[3] = f2bf(v.w);
            *(uint2*)(&la[row * BK + kc]) = pk.u2;
        }
        __syncthreads();

        // ---- fragments + 16 MFMAs ----
        short8 af[4], bf[4];
        #pragma unroll
        for (int tm = 0; tm < 4; ++tm)
            af[tm] = *(const short8*)(&la[(wm + tm * 16 + l16) * BK + quad * 8]);
        #pragma unroll
        for (int tn = 0; tn < 4; ++tn)
            bf[tn] = *(const short8*)(&lb[(wn + tn * 16 + l16) * BK + quad * 8]);
        #pragma unroll
        for (int tm = 0; tm < 4; ++tm)
            #pragma unroll
            for (int tn = 0; tn < 4; ++tn)
                acc[tm][tn] = __builtin_amdgcn_mfma_f32_16x16x32_bf16(
                    af[tm], bf[tn], acc[tm][tn], 0, 0, 0);
        __syncthreads();
    }

    // ---- epilogue: D[i = 4*quad + r][j = l16] ----
    #pragma unroll
    for (int tm = 0; tm < 4; ++tm) {
        #pragma unroll
        for (int tn = 0; tn < 4; ++tn) {
            const int row0 = bm * BM + wm + tm * 16 + quad * 4;
            const int col  = bn * BN + wn + tn * 16 + l16;
            #pragma unroll
            for (int r = 0; r < 4; ++r)
                C[(size_t)(row0 + r) * N_DIM + col] = acc[tm][tn][r];
        }
    }
}

extern "C" void kernel_launch(void* const* d_in, const int* in_sizes, int n_in,
                              void* d_out, int out_size, void* d_ws, size_t ws_size,
                              hipStream_t stream) {
    const float* x   = (const float*)d_in[0];   // (4,4096,2048) fp32
    const float* pop = (const float*)d_in[1];   // (2048,2048,32) fp32
    float* out = (float*)d_out;
    ushort* W = (ushort*)d_ws;                  // 2048*2048 bf16 = 8 MiB scratch

    // Phase 1: reduce population -> W (±1 bf16)
    const int total4 = N_DIM * K_DIM * SWARM / 4;     // 33,554,432 float4 loads
    swarm_reduce<<<total4 / 256, 256, 0, stream>>>((const float4*)pop, W);

    // Phase 2: C = x @ W^T via bf16 MFMA
    dim3 grid(M_DIM / BM, N_DIM / BN);   // 128 x 16 = 2048 blocks
    gemm_bt<<<grid, 256, 0, stream>>>(x, W, out);
}